// Round 5
// baseline (235.455 us; speedup 1.0000x reference)
//
#include <hip/hip_runtime.h>
#include <stdint.h>

#define NANCH 17064
#define BATCH 16
#define NCLS 80
#define KDET 1000
#define SCORE_THR 0.05f
#define IOU_THR 0.6f

typedef unsigned long long u64;
typedef unsigned int u32;

__device__ __forceinline__ float sigf(float x) { return 1.0f / (1.0f + expf(-x)); }

__device__ __forceinline__ void decode_anchor(int n, int& l, int& h, int& w) {
  if (n < 12800)      { l = 0; h = n >> 7;               w = n & 127; }
  else if (n < 16000) { l = 1; int r = n - 12800; h = r >> 6; w = r & 63; }
  else if (n < 16800) { l = 2; int r = n - 16000; h = r >> 5; w = r & 31; }
  else if (n < 17008) { l = 3; int r = n - 16800; h = r >> 4; w = r & 15; }
  else                { l = 4; int r = n - 17008; h = r >> 3; w = r & 7; }
}

// encode float for monotone u32 atomicMax
__device__ __forceinline__ u32 fenc(float f) {
  u32 u = __float_as_uint(f);
  return (u & 0x80000000u) ? ~u : (u | 0x80000000u);
}
__device__ __forceinline__ float fdec(u32 e) {
  u32 u = (e & 0x80000000u) ? (e ^ 0x80000000u) : ~e;
  return __uint_as_float(u);
}

// ---------------- kernel 1: per-anchor scores, 4 anchors/thread (float4) ----------------
// All level sizes (12800,3200,800,208,56) are divisible by 4 -> quads never straddle levels.
__global__ __launch_bounds__(256) void k_score(
    const float* __restrict__ cls0, const float* __restrict__ ctr0,
    const float* __restrict__ cls1, const float* __restrict__ ctr1,
    const float* __restrict__ cls2, const float* __restrict__ ctr2,
    const float* __restrict__ cls3, const float* __restrict__ ctr3,
    const float* __restrict__ cls4, const float* __restrict__ ctr4,
    u32* __restrict__ sb, u32* __restrict__ cl8)
{
  int q = blockIdx.x * blockDim.x + threadIdx.x;   // quad index
  if (q >= NANCH / 4) return;
  int b = blockIdx.y;
  int n = q * 4;
  const float* cp; const float* tp; int hw, off;
  if (n < 12800)      { cp = cls0; tp = ctr0; hw = 12800; off = n; }
  else if (n < 16000) { cp = cls1; tp = ctr1; hw = 3200;  off = n - 12800; }
  else if (n < 16800) { cp = cls2; tp = ctr2; hw = 800;   off = n - 16000; }
  else if (n < 17008) { cp = cls3; tp = ctr3; hw = 208;   off = n - 16800; }
  else                { cp = cls4; tp = ctr4; hw = 56;    off = n - 17008; }
  const float4* base = (const float4*)(cp + (size_t)b * NCLS * hw + off);
  const int s4 = hw >> 2;  // class stride in float4 units
  float m0 = -1.0f, m1 = -1.0f, m2 = -1.0f, m3 = -1.0f;
  int a0 = 0, a1 = 0, a2 = 0, a3 = 0;
  for (int c = 0; c < NCLS; ++c) {
    float4 v = base[(size_t)c * s4];
    float s0 = sigf(v.x), s1 = sigf(v.y), s2 = sigf(v.z), s3 = sigf(v.w);
    if (s0 > m0) { m0 = s0; a0 = c; }
    if (s1 > m1) { m1 = s1; a1 = c; }
    if (s2 > m2) { m2 = s2; a2 = c; }
    if (s3 > m3) { m3 = s3; a3 = c; }
  }
  float4 ctv = *(const float4*)(tp + (size_t)b * hw + off);
  float c0 = sigf(ctv.x), c1 = sigf(ctv.y), c2 = sigf(ctv.z), c3 = sigf(ctv.w);
  uint4 sv;
  sv.x = __float_as_uint(m0 * c0);
  sv.y = __float_as_uint(m1 * c1);
  sv.z = __float_as_uint(m2 * c2);
  sv.w = __float_as_uint(m3 * c3);
  *(uint4*)(sb + b * NANCH + n) = sv;
  cl8[(b * NANCH + n) >> 2] = (u32)a0 | ((u32)a1 << 8) | ((u32)a2 << 16) | ((u32)a3 << 24);
}

// ---------------- kernel 2: radix thresholds + candidate compaction ----------------
__global__ __launch_bounds__(1024) void k_topk(
    const u32* __restrict__ sb,
    u64* __restrict__ candG, int* __restrict__ cntG, u32* __restrict__ maxcG)
{
  __shared__ u32 hist[1024];
  __shared__ u32 wtot[16];
  __shared__ int s_T1, s_above, s_T2, s_cnt;

  const int tid = threadIdx.x;
  const int b = blockIdx.x;
  const int lane = tid & 63, wv = tid >> 6;
  const u32* sbb = sb + b * NANCH;

  // Phase 1: coarse histogram bits[31:22]
  hist[tid] = 0;
  __syncthreads();
  for (int n = tid; n < NANCH; n += 1024) atomicAdd(&hist[sbb[n] >> 22], 1u);
  __syncthreads();
  u32 h = hist[tid];
  u32 s = h;
  for (int d = 1; d < 64; d <<= 1) { u32 y = (u32)__shfl_down((int)s, d); if (lane + d < 64) s += y; }
  if (lane == 0) wtot[wv] = s;
  hist[tid] = 0;
  __syncthreads();
  {
    u32 add = 0;
    for (int w2 = wv + 1; w2 < 16; ++w2) add += wtot[w2];
    s += add;
  }
  if (s >= (u32)KDET && s - h < (u32)KDET) { s_T1 = tid; s_above = (int)(s - h); }
  __syncthreads();
  const int T1 = s_T1; const int above = s_above;

  // Phase 2: fine histogram bits[21:12] within bin T1
  for (int n = tid; n < NANCH; n += 1024) {
    u32 bits = sbb[n];
    if ((int)(bits >> 22) == T1) atomicAdd(&hist[(bits >> 12) & 1023u], 1u);
  }
  __syncthreads();
  h = hist[tid];
  s = h;
  for (int d = 1; d < 64; d <<= 1) { u32 y = (u32)__shfl_down((int)s, d); if (lane + d < 64) s += y; }
  if (lane == 0) wtot[wv] = s;
  __syncthreads();
  {
    u32 add = 0;
    for (int w2 = wv + 1; w2 < 16; ++w2) add += wtot[w2];
    s += add;
  }
  if (above + (int)s >= KDET && above + (int)(s - h) < KDET) s_T2 = tid;
  if (tid == 0) s_cnt = 0;
  __syncthreads();
  const int T2 = s_T2;

  // Phase 3: compact candidates to global
  for (int n = tid; n < NANCH; n += 1024) {
    u32 bits = sbb[n];
    int c1 = (int)(bits >> 22);
    bool cand = (c1 > T1) || (c1 == T1 && (int)((bits >> 12) & 1023u) >= T2);
    if (cand) {
      int pos = atomicAdd(&s_cnt, 1);
      if (pos < 2048) candG[b * 2048 + pos] = ((u64)bits << 32) | (u64)(u32)(~(u32)n);
    }
  }
  __syncthreads();
  if (tid == 0) {
    int C = s_cnt; if (C > 2048) C = 2048;
    cntG[b] = C;
    maxcG[b] = 0u;  // encoded -inf floor
  }
}

// ---------------- kernel 3: rank candidates, winners stage box/score/class ----------------
__global__ __launch_bounds__(256) void k_rank(
    const float* __restrict__ reg0, const float* __restrict__ reg1,
    const float* __restrict__ reg2, const float* __restrict__ reg3,
    const float* __restrict__ reg4,
    const unsigned char* __restrict__ cl8,
    const u64* __restrict__ candG, const int* __restrict__ cntG,
    float* __restrict__ scoreG, int* __restrict__ clsG, float4* __restrict__ boxG,
    u32* __restrict__ maxcG)
{
  __shared__ ulonglong2 keys2[1024];
  const int tid = threadIdx.x;
  const int c = blockIdx.x;   // 0..7
  const int b = blockIdx.y;
  const int lane = tid & 63;
  const int C = cntG[b];
  const u64* cand = candG + b * 2048;

  for (int i = tid; i < 1024; i += 256) {
    int i0 = 2 * i, i1 = 2 * i + 1;
    ulonglong2 v;
    v.x = (i0 < C) ? cand[i0] : 0ull;
    v.y = (i1 < C) ? cand[i1] : 0ull;
    keys2[i] = v;
  }
  __syncthreads();

  const int idx = c * 256 + tid;
  const bool active = (idx < C);
  u64 key = active ? cand[idx] : 0ull;

  int cnt = 0;
  const int Cp2 = ((C + 7) >> 3) << 2;   // ulonglong2 count, multiple of 4, covers C
  for (int s = 0; s < Cp2; s += 4) {
    ulonglong2 a0 = keys2[s], a1 = keys2[s + 1], a2 = keys2[s + 2], a3 = keys2[s + 3];
    cnt += (a0.x > key) + (a0.y > key) + (a1.x > key) + (a1.y > key)
         + (a2.x > key) + (a2.y > key) + (a3.x > key) + (a3.y > key);
  }

  u32 enc = 0u;
  if (active && cnt < KDET) {
    u32 bits = (u32)(key >> 32);
    int n = (int)(~(u32)(key & 0xFFFFFFFFull));
    float score = __uint_as_float(bits);
    int clsv = (int)cl8[b * NANCH + n] + 1;
    int l, hh, ww; decode_anchor(n, l, hh, ww);
    const float* rp; int W, ST, HF, hw;
    switch (l) {
      case 0: rp = reg0; W = 128; ST = 8;   HF = 4;  hw = 12800; break;
      case 1: rp = reg1; W = 64;  ST = 16;  HF = 8;  hw = 3200;  break;
      case 2: rp = reg2; W = 32;  ST = 32;  HF = 16; hw = 800;   break;
      case 3: rp = reg3; W = 16;  ST = 64;  HF = 32; hw = 208;   break;
      default: rp = reg4; W = 8;  ST = 128; HF = 64; hw = 56;    break;
    }
    float cx = (float)(ww * ST + HF);
    float cy = (float)(hh * ST + HF);
    const float* rb = rp + (size_t)b * 4 * hw + hh * W + ww;
    float r0 = rb[0], r1 = rb[hw], r2 = rb[2 * hw], r3 = rb[3 * hw];
    float4 bx = make_float4(cx - r0, cy - r1, cx + r2, cy + r3);
    int o = b * KDET + cnt;
    scoreG[o] = score; clsG[o] = clsv; boxG[o] = bx;
    enc = fenc(fmaxf(fmaxf(bx.x, bx.y), fmaxf(bx.z, bx.w)));
  }
  // wave-level max reduction of enc, one atomic per wave
  for (int d = 32; d > 0; d >>= 1) {
    u32 o = (u32)__shfl_xor((int)enc, d);
    enc = (o > enc) ? o : enc;
  }
  if (lane == 0 && enc != 0u) atomicMax(maxcG + b, enc);
}

// ---------------- kernel 4: transposed suppression matrix, register-only tiles ----------------
// matT[i][wc] bit j: (j < i) && iou(i,j) > thr
__global__ __launch_bounds__(256) void k_mat(
    const float4* __restrict__ boxG, const int* __restrict__ clsG,
    const u32* __restrict__ maxcG, u64* __restrict__ mat)
{
  const int tid = threadIdx.x, lane = tid & 63, wv = tid >> 6;
  const int b = blockIdx.y;
  const int tile = blockIdx.x * 4 + wv;
  if (tile >= 136) return;
  // triangular decode: tile = rt*(rt+1)/2 + wc, wc <= rt
  int rt = 0, rem = tile;
  while (rem >= rt + 1) { rem -= rt + 1; ++rt; }
  const int wc = rem;

  const float scale = fdec(maxcG[b]) + 1.0f;

  // column box j (per-lane, registers)
  const int j = (wc << 6) + lane;
  float jx1 = 0, jy1 = 0, jx2 = 0, jy2 = 0, aj = 0;
  if (j < KDET) {
    float4 bj = boxG[b * KDET + j];
    float off = (float)clsG[b * KDET + j] * scale;
    jx1 = bj.x + off; jy1 = bj.y + off; jx2 = bj.z + off; jy2 = bj.w + off;
    aj = (jx2 - jx1 + 1.0f) * (jy2 - jy1 + 1.0f);
  }
  // row boxes rt*64+lane (per-lane, broadcast by shfl below)
  const int ri = (rt << 6) + lane;
  float ix1 = 0, iy1 = 0, ix2 = 0, iy2 = 0;
  if (ri < KDET) {
    float4 bi = boxG[b * KDET + ri];
    float off = (float)clsG[b * KDET + ri] * scale;
    ix1 = bi.x + off; iy1 = bi.y + off; ix2 = bi.z + off; iy2 = bi.w + off;
  }

  u64 myword = 0ull;
  for (int r = 0; r < 64; ++r) {
    float x1 = __shfl(ix1, r), y1 = __shfl(iy1, r);
    float x2 = __shfl(ix2, r), y2 = __shfl(iy2, r);
    float ai = (x2 - x1 + 1.0f) * (y2 - y1 + 1.0f);
    int row = (rt << 6) + r;
    float xmin = fmaxf(x1, jx1), ymin = fmaxf(y1, jy1);
    float xmax = fminf(x2, jx2), ymax = fminf(y2, jy2);
    float inter = fmaxf(xmax - xmin, 0.0f) * fmaxf(ymax - ymin, 0.0f);
    float iou = inter / ((ai + aj) - inter);
    bool p = (j < row) && (j < KDET) && (iou > IOU_THR);
    u64 mm = __ballot(p);
    if (lane == r) myword = mm;
  }
  const int rowl = (rt << 6) + lane;
  if (rowl < KDET) mat[(size_t)b * (KDET * 16) + rowl * 16 + wc] = myword;
}

// ---------------- kernel 5: exact greedy NMS via Jacobi fixpoint + outputs ----------------
__global__ __launch_bounds__(1024) void k_nms(
    const u64* __restrict__ mat, const float* __restrict__ scoreG,
    const int* __restrict__ clsG, const float4* __restrict__ boxG,
    float* __restrict__ out)
{
  __shared__ u64 keptS[16];
  __shared__ int s_chg;
  const int tid = threadIdx.x;
  const int b = blockIdx.x;
  const int wv = tid >> 6, lane = tid & 63;

  float sc = (tid < KDET) ? scoreG[b * KDET + tid] : 0.0f;
  bool valid = (tid < KDET) && (sc >= SCORE_THR);

  u64 row[16];
  const u64* mrow = mat + (size_t)b * (KDET * 16) + (size_t)tid * 16;
  const int wtop = tid >> 6;
#pragma unroll
  for (int w = 0; w < 16; ++w)
    row[w] = (tid < KDET && w <= wtop) ? mrow[w] : 0ull;

  {
    u64 mb = __ballot(valid);
    if (lane == 0) keptS[wv] = mb;
  }
  __syncthreads();

  for (int it = 0; it < KDET + 1; ++it) {
    u64 sup = 0;
#pragma unroll
    for (int w = 0; w < 16; ++w) sup |= keptS[w] & row[w];
    bool nk = valid && (sup == 0ull);
    u64 nw = __ballot(nk);
    if (tid == 0) s_chg = 0;
    __syncthreads();
    if (lane == 0) {
      if (nw != keptS[wv]) s_chg = 1;
      keptS[wv] = nw;
    }
    __syncthreads();
    if (s_chg == 0) break;
  }

  if (tid < KDET) {
    bool kp = ((keptS[tid >> 6] >> (tid & 63)) & 1ull) != 0ull;
    int o1 = b * KDET + tid;
    out[o1] = kp ? sc : 0.0f;
    out[BATCH * KDET + o1] = kp ? (float)clsG[o1] : 0.0f;
    float4 bx = boxG[o1];
    float* ob = out + 2 * BATCH * KDET + (size_t)o1 * 4;
    ob[0] = kp ? bx.x : 0.0f;
    ob[1] = kp ? bx.y : 0.0f;
    ob[2] = kp ? bx.z : 0.0f;
    ob[3] = kp ? bx.w : 0.0f;
  }
}

extern "C" void kernel_launch(void* const* d_in, const int* in_sizes, int n_in,
                              void* d_out, int out_size, void* d_ws, size_t ws_size,
                              hipStream_t stream) {
  const float* cls[5]; const float* ctr[5]; const float* reg[5];
  for (int i = 0; i < 5; ++i) {
    cls[i] = (const float*)d_in[3 * i + 0];
    ctr[i] = (const float*)d_in[3 * i + 1];
    reg[i] = (const float*)d_in[3 * i + 2];
  }
  char* ws = (char*)d_ws;
  // mat region (0 .. 2,048,000) is overlaid by sb/cl8/candG, all dead before k_mat writes.
  u32* sb   = (u32*)ws;                                  // 1,092,096 B
  unsigned char* cl8 = (unsigned char*)(ws + 1092096);   //   273,024 B (dead after k_rank)
  u64* candG = (u64*)(ws + 1365120);                     //   262,144 B (dead after k_rank)
  u64* mat  = (u64*)ws;                                  // 2,048,000 B
  float*  scoreG = (float*) (ws + 2048000);              //    64,000 B
  int*    clsG   = (int*)   (ws + 2112000);              //    64,000 B
  float4* boxG   = (float4*)(ws + 2176000);              //   256,000 B
  int*    cntG   = (int*)   (ws + 2432000);              //        64 B
  u32*    maxcG  = (u32*)   (ws + 2432064);              //        64 B

  dim3 g1((NANCH / 4 + 255) / 256, BATCH);
  k_score<<<g1, 256, 0, stream>>>(cls[0], ctr[0], cls[1], ctr[1], cls[2], ctr[2],
                                  cls[3], ctr[3], cls[4], ctr[4], sb, (u32*)cl8);
  k_topk<<<BATCH, 1024, 0, stream>>>(sb, candG, cntG, maxcG);
  k_rank<<<dim3(8, BATCH), 256, 0, stream>>>(reg[0], reg[1], reg[2], reg[3], reg[4],
                                             cl8, candG, cntG, scoreG, clsG, boxG, maxcG);
  k_mat<<<dim3(34, BATCH), 256, 0, stream>>>(boxG, clsG, maxcG, mat);
  k_nms<<<BATCH, 1024, 0, stream>>>(mat, scoreG, clsG, boxG, (float*)d_out);
}

// Round 6
// 197.837 us; speedup vs baseline: 1.1901x; 1.1901x over previous
//
#include <hip/hip_runtime.h>
#include <stdint.h>

#define NANCH 17064
#define BATCH 16
#define NCLS 80
#define KDET 1000
#define SCORE_THR 0.05f
#define IOU_THR 0.6f

typedef unsigned long long u64;
typedef unsigned int u32;

__device__ __forceinline__ float sigf(float x) { return 1.0f / (1.0f + expf(-x)); }

__device__ __forceinline__ void decode_anchor(int n, int& l, int& h, int& w) {
  if (n < 12800)      { l = 0; h = n >> 7;               w = n & 127; }
  else if (n < 16000) { l = 1; int r = n - 12800; h = r >> 6; w = r & 63; }
  else if (n < 16800) { l = 2; int r = n - 16000; h = r >> 5; w = r & 31; }
  else if (n < 17008) { l = 3; int r = n - 16800; h = r >> 4; w = r & 15; }
  else                { l = 4; int r = n - 17008; h = r >> 3; w = r & 7; }
}

// encode float for monotone u32 atomicMax
__device__ __forceinline__ u32 fenc(float f) {
  u32 u = __float_as_uint(f);
  return (u & 0x80000000u) ? ~u : (u | 0x80000000u);
}
__device__ __forceinline__ float fdec(u32 e) {
  u32 u = (e & 0x80000000u) ? (e ^ 0x80000000u) : ~e;
  return __uint_as_float(u);
}

// ---------------- kernel 1: per-anchor scores ----------------
// Block (64,4): tid.x = quad lane (4 anchors via float4), tid.y = class block
// (20 classes). 4-deep load unroll for MLP; LDS merge preserves first-occurrence
// argmax tie semantics (strict >, ascending class-block order).
__global__ __launch_bounds__(256) void k_score(
    const float* __restrict__ cls0, const float* __restrict__ ctr0,
    const float* __restrict__ cls1, const float* __restrict__ ctr1,
    const float* __restrict__ cls2, const float* __restrict__ ctr2,
    const float* __restrict__ cls3, const float* __restrict__ ctr3,
    const float* __restrict__ cls4, const float* __restrict__ ctr4,
    u32* __restrict__ sb, u32* __restrict__ cl8)
{
  __shared__ float sm[4][64][5];   // [yblk][lane][anchor(+pad)]
  __shared__ u32 sa[4][64];        // packed 4×u8 argmax per quad

  const int x = threadIdx.x;       // 0..63
  const int y = threadIdx.y;       // 0..3
  const int b = blockIdx.y;
  int q = blockIdx.x * 64 + x;
  const bool act = (q < NANCH / 4);
  int qc = act ? q : (NANCH / 4 - 1);
  int n = qc * 4;

  const float* cp; const float* tp; int hw, off;
  if (n < 12800)      { cp = cls0; tp = ctr0; hw = 12800; off = n; }
  else if (n < 16000) { cp = cls1; tp = ctr1; hw = 3200;  off = n - 12800; }
  else if (n < 16800) { cp = cls2; tp = ctr2; hw = 800;   off = n - 16000; }
  else if (n < 17008) { cp = cls3; tp = ctr3; hw = 208;   off = n - 16800; }
  else                { cp = cls4; tp = ctr4; hw = 56;    off = n - 17008; }
  const float4* base = (const float4*)(cp + (size_t)b * NCLS * hw + off);
  const int s4 = hw >> 2;

  float m0 = -1.0f, m1 = -1.0f, m2 = -1.0f, m3 = -1.0f;
  int a0 = 0, a1 = 0, a2 = 0, a3 = 0;
  const int cb = y * 20;
#pragma unroll
  for (int cc = 0; cc < 20; cc += 4) {
    int c = cb + cc;
    float4 v0 = base[(size_t)(c + 0) * s4];
    float4 v1 = base[(size_t)(c + 1) * s4];
    float4 v2 = base[(size_t)(c + 2) * s4];
    float4 v3 = base[(size_t)(c + 3) * s4];
    float s;
    s = sigf(v0.x); if (s > m0) { m0 = s; a0 = c; }
    s = sigf(v0.y); if (s > m1) { m1 = s; a1 = c; }
    s = sigf(v0.z); if (s > m2) { m2 = s; a2 = c; }
    s = sigf(v0.w); if (s > m3) { m3 = s; a3 = c; }
    s = sigf(v1.x); if (s > m0) { m0 = s; a0 = c + 1; }
    s = sigf(v1.y); if (s > m1) { m1 = s; a1 = c + 1; }
    s = sigf(v1.z); if (s > m2) { m2 = s; a2 = c + 1; }
    s = sigf(v1.w); if (s > m3) { m3 = s; a3 = c + 1; }
    s = sigf(v2.x); if (s > m0) { m0 = s; a0 = c + 2; }
    s = sigf(v2.y); if (s > m1) { m1 = s; a1 = c + 2; }
    s = sigf(v2.z); if (s > m2) { m2 = s; a2 = c + 2; }
    s = sigf(v2.w); if (s > m3) { m3 = s; a3 = c + 2; }
    s = sigf(v3.x); if (s > m0) { m0 = s; a0 = c + 3; }
    s = sigf(v3.y); if (s > m1) { m1 = s; a1 = c + 3; }
    s = sigf(v3.z); if (s > m2) { m2 = s; a2 = c + 3; }
    s = sigf(v3.w); if (s > m3) { m3 = s; a3 = c + 3; }
  }
  sm[y][x][0] = m0; sm[y][x][1] = m1; sm[y][x][2] = m2; sm[y][x][3] = m3;
  sa[y][x] = (u32)a0 | ((u32)a1 << 8) | ((u32)a2 << 16) | ((u32)a3 << 24);
  __syncthreads();

  if (y == 0 && act) {
#pragma unroll
    for (int k = 1; k < 4; ++k) {
      u32 pk = sa[k][x];
      float t;
      t = sm[k][x][0]; if (t > m0) { m0 = t; a0 = (int)(pk & 0xffu); }
      t = sm[k][x][1]; if (t > m1) { m1 = t; a1 = (int)((pk >> 8) & 0xffu); }
      t = sm[k][x][2]; if (t > m2) { m2 = t; a2 = (int)((pk >> 16) & 0xffu); }
      t = sm[k][x][3]; if (t > m3) { m3 = t; a3 = (int)((pk >> 24) & 0xffu); }
    }
    float4 ctv = *(const float4*)(tp + (size_t)b * hw + off);
    uint4 sv;
    sv.x = __float_as_uint(m0 * sigf(ctv.x));
    sv.y = __float_as_uint(m1 * sigf(ctv.y));
    sv.z = __float_as_uint(m2 * sigf(ctv.z));
    sv.w = __float_as_uint(m3 * sigf(ctv.w));
    *(uint4*)(sb + b * NANCH + n) = sv;
    cl8[(b * NANCH + n) >> 2] = (u32)a0 | ((u32)a1 << 8) | ((u32)a2 << 16) | ((u32)a3 << 24);
  }
}

// ---------------- kernel 2: radix thresholds + candidate compaction ----------------
__global__ __launch_bounds__(1024) void k_topk(
    const u32* __restrict__ sb,
    u64* __restrict__ candG, int* __restrict__ cntG, u32* __restrict__ maxcG)
{
  __shared__ u32 hist[1024];
  __shared__ u32 wtot[16];
  __shared__ int s_T1, s_above, s_T2, s_cnt;

  const int tid = threadIdx.x;
  const int b = blockIdx.x;
  const int lane = tid & 63, wv = tid >> 6;
  const u32* sbb = sb + b * NANCH;

  // Phase 1: coarse histogram bits[31:22]
  hist[tid] = 0;
  __syncthreads();
  for (int n = tid; n < NANCH; n += 1024) atomicAdd(&hist[sbb[n] >> 22], 1u);
  __syncthreads();
  u32 h = hist[tid];
  u32 s = h;
  for (int d = 1; d < 64; d <<= 1) { u32 y = (u32)__shfl_down((int)s, d); if (lane + d < 64) s += y; }
  if (lane == 0) wtot[wv] = s;
  hist[tid] = 0;
  __syncthreads();
  {
    u32 add = 0;
    for (int w2 = wv + 1; w2 < 16; ++w2) add += wtot[w2];
    s += add;
  }
  if (s >= (u32)KDET && s - h < (u32)KDET) { s_T1 = tid; s_above = (int)(s - h); }
  __syncthreads();
  const int T1 = s_T1; const int above = s_above;

  // Phase 2: fine histogram bits[21:12] within bin T1
  for (int n = tid; n < NANCH; n += 1024) {
    u32 bits = sbb[n];
    if ((int)(bits >> 22) == T1) atomicAdd(&hist[(bits >> 12) & 1023u], 1u);
  }
  __syncthreads();
  h = hist[tid];
  s = h;
  for (int d = 1; d < 64; d <<= 1) { u32 y = (u32)__shfl_down((int)s, d); if (lane + d < 64) s += y; }
  if (lane == 0) wtot[wv] = s;
  __syncthreads();
  {
    u32 add = 0;
    for (int w2 = wv + 1; w2 < 16; ++w2) add += wtot[w2];
    s += add;
  }
  if (above + (int)s >= KDET && above + (int)(s - h) < KDET) s_T2 = tid;
  if (tid == 0) s_cnt = 0;
  __syncthreads();
  const int T2 = s_T2;

  // Phase 3: compact candidates to global
  for (int n = tid; n < NANCH; n += 1024) {
    u32 bits = sbb[n];
    int c1 = (int)(bits >> 22);
    bool cand = (c1 > T1) || (c1 == T1 && (int)((bits >> 12) & 1023u) >= T2);
    if (cand) {
      int pos = atomicAdd(&s_cnt, 1);
      if (pos < 2048) candG[b * 2048 + pos] = ((u64)bits << 32) | (u64)(u32)(~(u32)n);
    }
  }
  __syncthreads();
  if (tid == 0) {
    int C = s_cnt; if (C > 2048) C = 2048;
    cntG[b] = C;
    maxcG[b] = 0u;  // encoded -inf floor
  }
}

// ---------------- kernel 3: rank candidates, winners stage box/score/class ----------------
__global__ __launch_bounds__(256) void k_rank(
    const float* __restrict__ reg0, const float* __restrict__ reg1,
    const float* __restrict__ reg2, const float* __restrict__ reg3,
    const float* __restrict__ reg4,
    const unsigned char* __restrict__ cl8,
    const u64* __restrict__ candG, const int* __restrict__ cntG,
    float* __restrict__ scoreG, int* __restrict__ clsG, float4* __restrict__ boxG,
    u32* __restrict__ maxcG)
{
  __shared__ ulonglong2 keys2[1024];
  const int tid = threadIdx.x;
  const int c = blockIdx.x;   // 0..7
  const int b = blockIdx.y;
  const int lane = tid & 63;
  const int C = cntG[b];
  const u64* cand = candG + b * 2048;

  for (int i = tid; i < 1024; i += 256) {
    int i0 = 2 * i, i1 = 2 * i + 1;
    ulonglong2 v;
    v.x = (i0 < C) ? cand[i0] : 0ull;
    v.y = (i1 < C) ? cand[i1] : 0ull;
    keys2[i] = v;
  }
  __syncthreads();

  const int idx = c * 256 + tid;
  const bool active = (idx < C);
  u64 key = active ? cand[idx] : 0ull;

  int cnt = 0;
  const int Cp2 = ((C + 7) >> 3) << 2;
  for (int s = 0; s < Cp2; s += 4) {
    ulonglong2 a0 = keys2[s], a1 = keys2[s + 1], a2 = keys2[s + 2], a3 = keys2[s + 3];
    cnt += (a0.x > key) + (a0.y > key) + (a1.x > key) + (a1.y > key)
         + (a2.x > key) + (a2.y > key) + (a3.x > key) + (a3.y > key);
  }

  u32 enc = 0u;
  if (active && cnt < KDET) {
    u32 bits = (u32)(key >> 32);
    int n = (int)(~(u32)(key & 0xFFFFFFFFull));
    float score = __uint_as_float(bits);
    int clsv = (int)cl8[b * NANCH + n] + 1;
    int l, hh, ww; decode_anchor(n, l, hh, ww);
    const float* rp; int W, ST, HF, hw;
    switch (l) {
      case 0: rp = reg0; W = 128; ST = 8;   HF = 4;  hw = 12800; break;
      case 1: rp = reg1; W = 64;  ST = 16;  HF = 8;  hw = 3200;  break;
      case 2: rp = reg2; W = 32;  ST = 32;  HF = 16; hw = 800;   break;
      case 3: rp = reg3; W = 16;  ST = 64;  HF = 32; hw = 208;   break;
      default: rp = reg4; W = 8;  ST = 128; HF = 64; hw = 56;    break;
    }
    float cx = (float)(ww * ST + HF);
    float cy = (float)(hh * ST + HF);
    const float* rb = rp + (size_t)b * 4 * hw + hh * W + ww;
    float r0 = rb[0], r1 = rb[hw], r2 = rb[2 * hw], r3 = rb[3 * hw];
    float4 bx = make_float4(cx - r0, cy - r1, cx + r2, cy + r3);
    int o = b * KDET + cnt;
    scoreG[o] = score; clsG[o] = clsv; boxG[o] = bx;
    enc = fenc(fmaxf(fmaxf(bx.x, bx.y), fmaxf(bx.z, bx.w)));
  }
  for (int d = 32; d > 0; d >>= 1) {
    u32 o = (u32)__shfl_xor((int)enc, d);
    enc = (o > enc) ? o : enc;
  }
  if (lane == 0 && enc != 0u) atomicMax(maxcG + b, enc);
}

// ---------------- kernel 4: transposed suppression matrix, register-only tiles ----------------
// matT[i][wc] bit j: (j < i) && iou(i,j) > thr
__global__ __launch_bounds__(256) void k_mat(
    const float4* __restrict__ boxG, const int* __restrict__ clsG,
    const u32* __restrict__ maxcG, u64* __restrict__ mat)
{
  const int tid = threadIdx.x, lane = tid & 63, wv = tid >> 6;
  const int b = blockIdx.y;
  const int tile = blockIdx.x * 4 + wv;
  if (tile >= 136) return;
  int rt = 0, rem = tile;
  while (rem >= rt + 1) { rem -= rt + 1; ++rt; }
  const int wc = rem;

  const float scale = fdec(maxcG[b]) + 1.0f;

  const int j = (wc << 6) + lane;
  float jx1 = 0, jy1 = 0, jx2 = 0, jy2 = 0, aj = 0;
  if (j < KDET) {
    float4 bj = boxG[b * KDET + j];
    float off = (float)clsG[b * KDET + j] * scale;
    jx1 = bj.x + off; jy1 = bj.y + off; jx2 = bj.z + off; jy2 = bj.w + off;
    aj = (jx2 - jx1 + 1.0f) * (jy2 - jy1 + 1.0f);
  }
  const int ri = (rt << 6) + lane;
  float ix1 = 0, iy1 = 0, ix2 = 0, iy2 = 0;
  if (ri < KDET) {
    float4 bi = boxG[b * KDET + ri];
    float off = (float)clsG[b * KDET + ri] * scale;
    ix1 = bi.x + off; iy1 = bi.y + off; ix2 = bi.z + off; iy2 = bi.w + off;
  }

  u64 myword = 0ull;
  for (int r = 0; r < 64; ++r) {
    float x1 = __shfl(ix1, r), y1 = __shfl(iy1, r);
    float x2 = __shfl(ix2, r), y2 = __shfl(iy2, r);
    float ai = (x2 - x1 + 1.0f) * (y2 - y1 + 1.0f);
    int row = (rt << 6) + r;
    float xmin = fmaxf(x1, jx1), ymin = fmaxf(y1, jy1);
    float xmax = fminf(x2, jx2), ymax = fminf(y2, jy2);
    float inter = fmaxf(xmax - xmin, 0.0f) * fmaxf(ymax - ymin, 0.0f);
    float iou = inter / ((ai + aj) - inter);
    bool p = (j < row) && (j < KDET) && (iou > IOU_THR);
    u64 mm = __ballot(p);
    if (lane == r) myword = mm;
  }
  const int rowl = (rt << 6) + lane;
  if (rowl < KDET) mat[(size_t)b * (KDET * 16) + rowl * 16 + wc] = myword;
}

// ---------------- kernel 5: exact greedy NMS via Jacobi fixpoint + outputs ----------------
__global__ __launch_bounds__(1024) void k_nms(
    const u64* __restrict__ mat, const float* __restrict__ scoreG,
    const int* __restrict__ clsG, const float4* __restrict__ boxG,
    float* __restrict__ out)
{
  __shared__ u64 keptS[16];
  __shared__ int s_chg;
  const int tid = threadIdx.x;
  const int b = blockIdx.x;
  const int wv = tid >> 6, lane = tid & 63;

  float sc = (tid < KDET) ? scoreG[b * KDET + tid] : 0.0f;
  bool valid = (tid < KDET) && (sc >= SCORE_THR);

  u64 row[16];
  const u64* mrow = mat + (size_t)b * (KDET * 16) + (size_t)tid * 16;
  const int wtop = tid >> 6;
#pragma unroll
  for (int w = 0; w < 16; ++w)
    row[w] = (tid < KDET && w <= wtop) ? mrow[w] : 0ull;

  {
    u64 mb = __ballot(valid);
    if (lane == 0) keptS[wv] = mb;
  }
  __syncthreads();

  for (int it = 0; it < KDET + 1; ++it) {
    u64 sup = 0;
#pragma unroll
    for (int w = 0; w < 16; ++w) sup |= keptS[w] & row[w];
    bool nk = valid && (sup == 0ull);
    u64 nw = __ballot(nk);
    if (tid == 0) s_chg = 0;
    __syncthreads();
    if (lane == 0) {
      if (nw != keptS[wv]) s_chg = 1;
      keptS[wv] = nw;
    }
    __syncthreads();
    if (s_chg == 0) break;
  }

  if (tid < KDET) {
    bool kp = ((keptS[tid >> 6] >> (tid & 63)) & 1ull) != 0ull;
    int o1 = b * KDET + tid;
    out[o1] = kp ? sc : 0.0f;
    out[BATCH * KDET + o1] = kp ? (float)clsG[o1] : 0.0f;
    float4 bx = boxG[o1];
    float* ob = out + 2 * BATCH * KDET + (size_t)o1 * 4;
    ob[0] = kp ? bx.x : 0.0f;
    ob[1] = kp ? bx.y : 0.0f;
    ob[2] = kp ? bx.z : 0.0f;
    ob[3] = kp ? bx.w : 0.0f;
  }
}

extern "C" void kernel_launch(void* const* d_in, const int* in_sizes, int n_in,
                              void* d_out, int out_size, void* d_ws, size_t ws_size,
                              hipStream_t stream) {
  const float* cls[5]; const float* ctr[5]; const float* reg[5];
  for (int i = 0; i < 5; ++i) {
    cls[i] = (const float*)d_in[3 * i + 0];
    ctr[i] = (const float*)d_in[3 * i + 1];
    reg[i] = (const float*)d_in[3 * i + 2];
  }
  char* ws = (char*)d_ws;
  // mat region (0 .. 2,048,000) is overlaid by sb/cl8/candG, all dead before k_mat writes.
  u32* sb   = (u32*)ws;                                  // 1,092,096 B
  unsigned char* cl8 = (unsigned char*)(ws + 1092096);   //   273,024 B (dead after k_rank)
  u64* candG = (u64*)(ws + 1365120);                     //   262,144 B (dead after k_rank)
  u64* mat  = (u64*)ws;                                  // 2,048,000 B
  float*  scoreG = (float*) (ws + 2048000);              //    64,000 B
  int*    clsG   = (int*)   (ws + 2112000);              //    64,000 B
  float4* boxG   = (float4*)(ws + 2176000);              //   256,000 B
  int*    cntG   = (int*)   (ws + 2432000);              //        64 B
  u32*    maxcG  = (u32*)   (ws + 2432064);              //        64 B

  dim3 g1((NANCH / 4 + 63) / 64, BATCH);
  k_score<<<g1, dim3(64, 4), 0, stream>>>(cls[0], ctr[0], cls[1], ctr[1], cls[2], ctr[2],
                                          cls[3], ctr[3], cls[4], ctr[4], sb, (u32*)cl8);
  k_topk<<<BATCH, 1024, 0, stream>>>(sb, candG, cntG, maxcG);
  k_rank<<<dim3(8, BATCH), 256, 0, stream>>>(reg[0], reg[1], reg[2], reg[3], reg[4],
                                             cl8, candG, cntG, scoreG, clsG, boxG, maxcG);
  k_mat<<<dim3(34, BATCH), 256, 0, stream>>>(boxG, clsG, maxcG, mat);
  k_nms<<<BATCH, 1024, 0, stream>>>(mat, scoreG, clsG, boxG, (float*)d_out);
}

// Round 7
// 195.035 us; speedup vs baseline: 1.2072x; 1.0144x over previous
//
#include <hip/hip_runtime.h>
#include <stdint.h>

#define NANCH 17064
#define BATCH 16
#define NCLS 80
#define KDET 1000
#define SCORE_THR 0.05f
#define IOU_THR 0.6f

typedef unsigned long long u64;
typedef unsigned int u32;

__device__ __forceinline__ float sigf(float x) { return 1.0f / (1.0f + expf(-x)); }

__device__ __forceinline__ void decode_anchor(int n, int& l, int& h, int& w) {
  if (n < 12800)      { l = 0; h = n >> 7;               w = n & 127; }
  else if (n < 16000) { l = 1; int r = n - 12800; h = r >> 6; w = r & 63; }
  else if (n < 16800) { l = 2; int r = n - 16000; h = r >> 5; w = r & 31; }
  else if (n < 17008) { l = 3; int r = n - 16800; h = r >> 4; w = r & 15; }
  else                { l = 4; int r = n - 17008; h = r >> 3; w = r & 7; }
}

// encode float for monotone u32 atomicMax
__device__ __forceinline__ u32 fenc(float f) {
  u32 u = __float_as_uint(f);
  return (u & 0x80000000u) ? ~u : (u | 0x80000000u);
}
__device__ __forceinline__ float fdec(u32 e) {
  u32 u = (e & 0x80000000u) ? (e ^ 0x80000000u) : ~e;
  return __uint_as_float(u);
}

// ---------------- kernel 1: per-anchor scores ----------------
// Block (64,4): tid.x = quad lane (4 anchors via float4), tid.y = class block
// (20 classes). ALL 20 class loads issued before any sigmoid (ILP=20 covers
// ~900cy HBM latency at 4 waves/SIMD). LDS merge preserves first-occurrence
// argmax tie semantics (strict >, ascending class-block order).
__global__ __launch_bounds__(256, 4) void k_score(
    const float* __restrict__ cls0, const float* __restrict__ ctr0,
    const float* __restrict__ cls1, const float* __restrict__ ctr1,
    const float* __restrict__ cls2, const float* __restrict__ ctr2,
    const float* __restrict__ cls3, const float* __restrict__ ctr3,
    const float* __restrict__ cls4, const float* __restrict__ ctr4,
    u32* __restrict__ sb, u32* __restrict__ cl8)
{
  __shared__ float sm[4][64][5];   // [yblk][lane][anchor(+pad)]
  __shared__ u32 sa[4][64];        // packed 4×u8 argmax per quad

  const int x = threadIdx.x;       // 0..63
  const int y = threadIdx.y;       // 0..3
  const int b = blockIdx.y;
  int q = blockIdx.x * 64 + x;
  const bool act = (q < NANCH / 4);
  int qc = act ? q : (NANCH / 4 - 1);
  int n = qc * 4;

  const float* cp; const float* tp; int hw, off;
  if (n < 12800)      { cp = cls0; tp = ctr0; hw = 12800; off = n; }
  else if (n < 16000) { cp = cls1; tp = ctr1; hw = 3200;  off = n - 12800; }
  else if (n < 16800) { cp = cls2; tp = ctr2; hw = 800;   off = n - 16000; }
  else if (n < 17008) { cp = cls3; tp = ctr3; hw = 208;   off = n - 16800; }
  else                { cp = cls4; tp = ctr4; hw = 56;    off = n - 17008; }
  const float4* base = (const float4*)(cp + (size_t)b * NCLS * hw + off);
  const int s4 = hw >> 2;
  const int cb = y * 20;

  // issue all 20 loads up-front
  float4 v[20];
#pragma unroll
  for (int cc = 0; cc < 20; ++cc) v[cc] = base[(size_t)(cb + cc) * s4];

  float m0 = -1.0f, m1 = -1.0f, m2 = -1.0f, m3 = -1.0f;
  int a0 = 0, a1 = 0, a2 = 0, a3 = 0;
#pragma unroll
  for (int cc = 0; cc < 20; ++cc) {
    int c = cb + cc;
    float s;
    s = sigf(v[cc].x); if (s > m0) { m0 = s; a0 = c; }
    s = sigf(v[cc].y); if (s > m1) { m1 = s; a1 = c; }
    s = sigf(v[cc].z); if (s > m2) { m2 = s; a2 = c; }
    s = sigf(v[cc].w); if (s > m3) { m3 = s; a3 = c; }
  }
  sm[y][x][0] = m0; sm[y][x][1] = m1; sm[y][x][2] = m2; sm[y][x][3] = m3;
  sa[y][x] = (u32)a0 | ((u32)a1 << 8) | ((u32)a2 << 16) | ((u32)a3 << 24);
  __syncthreads();

  if (y == 0 && act) {
#pragma unroll
    for (int k = 1; k < 4; ++k) {
      u32 pk = sa[k][x];
      float t;
      t = sm[k][x][0]; if (t > m0) { m0 = t; a0 = (int)(pk & 0xffu); }
      t = sm[k][x][1]; if (t > m1) { m1 = t; a1 = (int)((pk >> 8) & 0xffu); }
      t = sm[k][x][2]; if (t > m2) { m2 = t; a2 = (int)((pk >> 16) & 0xffu); }
      t = sm[k][x][3]; if (t > m3) { m3 = t; a3 = (int)((pk >> 24) & 0xffu); }
    }
    float4 ctv = *(const float4*)(tp + (size_t)b * hw + off);
    uint4 sv;
    sv.x = __float_as_uint(m0 * sigf(ctv.x));
    sv.y = __float_as_uint(m1 * sigf(ctv.y));
    sv.z = __float_as_uint(m2 * sigf(ctv.z));
    sv.w = __float_as_uint(m3 * sigf(ctv.w));
    *(uint4*)(sb + b * NANCH + n) = sv;
    cl8[(b * NANCH + n) >> 2] = (u32)a0 | ((u32)a1 << 8) | ((u32)a2 << 16) | ((u32)a3 << 24);
  }
}

// ---------------- kernel 2: radix thresholds + candidate compaction ----------------
// Scores register-cached: ONE global read pass instead of three.
__global__ __launch_bounds__(1024) void k_topk(
    const u32* __restrict__ sb,
    u64* __restrict__ candG, int* __restrict__ cntG, u32* __restrict__ maxcG)
{
  __shared__ u32 hist[1024];
  __shared__ u32 wtot[16];
  __shared__ int s_T1, s_above, s_T2, s_cnt;

  const int tid = threadIdx.x;
  const int b = blockIdx.x;
  const int lane = tid & 63, wv = tid >> 6;
  const u32* sbb = sb + b * NANCH;

  // register cache: up to 17 scores/thread
  u32 sc[17];
#pragma unroll
  for (int k = 0; k < 17; ++k) {
    int n = tid + (k << 10);
    sc[k] = (n < NANCH) ? sbb[n] : 0u;
  }

  // Phase 1: coarse histogram bits[31:22]
  hist[tid] = 0;
  __syncthreads();
#pragma unroll
  for (int k = 0; k < 17; ++k) {
    int n = tid + (k << 10);
    if (n < NANCH) atomicAdd(&hist[sc[k] >> 22], 1u);
  }
  __syncthreads();
  u32 h = hist[tid];
  u32 s = h;
  for (int d = 1; d < 64; d <<= 1) { u32 y = (u32)__shfl_down((int)s, d); if (lane + d < 64) s += y; }
  if (lane == 0) wtot[wv] = s;
  hist[tid] = 0;
  __syncthreads();
  {
    u32 add = 0;
    for (int w2 = wv + 1; w2 < 16; ++w2) add += wtot[w2];
    s += add;
  }
  if (s >= (u32)KDET && s - h < (u32)KDET) { s_T1 = tid; s_above = (int)(s - h); }
  __syncthreads();
  const int T1 = s_T1; const int above = s_above;

  // Phase 2: fine histogram bits[21:12] within bin T1
#pragma unroll
  for (int k = 0; k < 17; ++k) {
    int n = tid + (k << 10);
    u32 bits = sc[k];
    if (n < NANCH && (int)(bits >> 22) == T1) atomicAdd(&hist[(bits >> 12) & 1023u], 1u);
  }
  __syncthreads();
  h = hist[tid];
  s = h;
  for (int d = 1; d < 64; d <<= 1) { u32 y = (u32)__shfl_down((int)s, d); if (lane + d < 64) s += y; }
  if (lane == 0) wtot[wv] = s;
  __syncthreads();
  {
    u32 add = 0;
    for (int w2 = wv + 1; w2 < 16; ++w2) add += wtot[w2];
    s += add;
  }
  if (above + (int)s >= KDET && above + (int)(s - h) < KDET) s_T2 = tid;
  if (tid == 0) s_cnt = 0;
  __syncthreads();
  const int T2 = s_T2;

  // Phase 3: compact candidates to global (order irrelevant; rank fixes position)
#pragma unroll
  for (int k = 0; k < 17; ++k) {
    int n = tid + (k << 10);
    u32 bits = sc[k];
    int c1 = (int)(bits >> 22);
    bool cand = (n < NANCH) &&
                ((c1 > T1) || (c1 == T1 && (int)((bits >> 12) & 1023u) >= T2));
    if (cand) {
      int pos = atomicAdd(&s_cnt, 1);
      if (pos < 2048) candG[b * 2048 + pos] = ((u64)bits << 32) | (u64)(u32)(~(u32)n);
    }
  }
  __syncthreads();
  if (tid == 0) {
    int C = s_cnt; if (C > 2048) C = 2048;
    cntG[b] = C;
    maxcG[b] = 0u;  // encoded -inf floor
  }
}

// ---------------- kernel 3: rank candidates, winners stage box/score/class ----------------
__global__ __launch_bounds__(256) void k_rank(
    const float* __restrict__ reg0, const float* __restrict__ reg1,
    const float* __restrict__ reg2, const float* __restrict__ reg3,
    const float* __restrict__ reg4,
    const unsigned char* __restrict__ cl8,
    const u64* __restrict__ candG, const int* __restrict__ cntG,
    float* __restrict__ scoreG, int* __restrict__ clsG, float4* __restrict__ boxG,
    u32* __restrict__ maxcG)
{
  __shared__ ulonglong2 keys2[1024];
  const int tid = threadIdx.x;
  const int c = blockIdx.x;   // 0..7
  const int b = blockIdx.y;
  const int lane = tid & 63;
  const int C = cntG[b];
  const u64* cand = candG + b * 2048;

  for (int i = tid; i < 1024; i += 256) {
    int i0 = 2 * i, i1 = 2 * i + 1;
    ulonglong2 v;
    v.x = (i0 < C) ? cand[i0] : 0ull;
    v.y = (i1 < C) ? cand[i1] : 0ull;
    keys2[i] = v;
  }
  __syncthreads();

  const int idx = c * 256 + tid;
  const bool active = (idx < C);
  u64 key = active ? cand[idx] : 0ull;

  int cnt = 0;
  const int Cp2 = ((C + 7) >> 3) << 2;
  for (int s = 0; s < Cp2; s += 4) {
    ulonglong2 a0 = keys2[s], a1 = keys2[s + 1], a2 = keys2[s + 2], a3 = keys2[s + 3];
    cnt += (a0.x > key) + (a0.y > key) + (a1.x > key) + (a1.y > key)
         + (a2.x > key) + (a2.y > key) + (a3.x > key) + (a3.y > key);
  }

  u32 enc = 0u;
  if (active && cnt < KDET) {
    u32 bits = (u32)(key >> 32);
    int n = (int)(~(u32)(key & 0xFFFFFFFFull));
    float score = __uint_as_float(bits);
    int clsv = (int)cl8[b * NANCH + n] + 1;
    int l, hh, ww; decode_anchor(n, l, hh, ww);
    const float* rp; int W, ST, HF, hw;
    switch (l) {
      case 0: rp = reg0; W = 128; ST = 8;   HF = 4;  hw = 12800; break;
      case 1: rp = reg1; W = 64;  ST = 16;  HF = 8;  hw = 3200;  break;
      case 2: rp = reg2; W = 32;  ST = 32;  HF = 16; hw = 800;   break;
      case 3: rp = reg3; W = 16;  ST = 64;  HF = 32; hw = 208;   break;
      default: rp = reg4; W = 8;  ST = 128; HF = 64; hw = 56;    break;
    }
    float cx = (float)(ww * ST + HF);
    float cy = (float)(hh * ST + HF);
    const float* rb = rp + (size_t)b * 4 * hw + hh * W + ww;
    float r0 = rb[0], r1 = rb[hw], r2 = rb[2 * hw], r3 = rb[3 * hw];
    float4 bx = make_float4(cx - r0, cy - r1, cx + r2, cy + r3);
    int o = b * KDET + cnt;
    scoreG[o] = score; clsG[o] = clsv; boxG[o] = bx;
    enc = fenc(fmaxf(fmaxf(bx.x, bx.y), fmaxf(bx.z, bx.w)));
  }
  for (int d = 32; d > 0; d >>= 1) {
    u32 o = (u32)__shfl_xor((int)enc, d);
    enc = (o > enc) ? o : enc;
  }
  if (lane == 0 && enc != 0u) atomicMax(maxcG + b, enc);
}

// ---------------- kernel 4: transposed suppression matrix, register-only tiles ----------------
// matT[i][wc] bit j: (j < i) && iou(i,j) > thr
__global__ __launch_bounds__(256) void k_mat(
    const float4* __restrict__ boxG, const int* __restrict__ clsG,
    const u32* __restrict__ maxcG, u64* __restrict__ mat)
{
  const int tid = threadIdx.x, lane = tid & 63, wv = tid >> 6;
  const int b = blockIdx.y;
  const int tile = blockIdx.x * 4 + wv;
  if (tile >= 136) return;
  int rt = 0, rem = tile;
  while (rem >= rt + 1) { rem -= rt + 1; ++rt; }
  const int wc = rem;

  const float scale = fdec(maxcG[b]) + 1.0f;

  const int j = (wc << 6) + lane;
  float jx1 = 0, jy1 = 0, jx2 = 0, jy2 = 0, aj = 0;
  if (j < KDET) {
    float4 bj = boxG[b * KDET + j];
    float off = (float)clsG[b * KDET + j] * scale;
    jx1 = bj.x + off; jy1 = bj.y + off; jx2 = bj.z + off; jy2 = bj.w + off;
    aj = (jx2 - jx1 + 1.0f) * (jy2 - jy1 + 1.0f);
  }
  const int ri = (rt << 6) + lane;
  float ix1 = 0, iy1 = 0, ix2 = 0, iy2 = 0;
  if (ri < KDET) {
    float4 bi = boxG[b * KDET + ri];
    float off = (float)clsG[b * KDET + ri] * scale;
    ix1 = bi.x + off; iy1 = bi.y + off; ix2 = bi.z + off; iy2 = bi.w + off;
  }

  u64 myword = 0ull;
  for (int r = 0; r < 64; ++r) {
    float x1 = __shfl(ix1, r), y1 = __shfl(iy1, r);
    float x2 = __shfl(ix2, r), y2 = __shfl(iy2, r);
    float ai = (x2 - x1 + 1.0f) * (y2 - y1 + 1.0f);
    int row = (rt << 6) + r;
    float xmin = fmaxf(x1, jx1), ymin = fmaxf(y1, jy1);
    float xmax = fminf(x2, jx2), ymax = fminf(y2, jy2);
    float inter = fmaxf(xmax - xmin, 0.0f) * fmaxf(ymax - ymin, 0.0f);
    float iou = inter / ((ai + aj) - inter);
    bool p = (j < row) && (j < KDET) && (iou > IOU_THR);
    u64 mm = __ballot(p);
    if (lane == r) myword = mm;
  }
  const int rowl = (rt << 6) + lane;
  if (rowl < KDET) mat[(size_t)b * (KDET * 16) + rowl * 16 + wc] = myword;
}

// ---------------- kernel 5: exact greedy NMS via Jacobi fixpoint + outputs ----------------
__global__ __launch_bounds__(1024) void k_nms(
    const u64* __restrict__ mat, const float* __restrict__ scoreG,
    const int* __restrict__ clsG, const float4* __restrict__ boxG,
    float* __restrict__ out)
{
  __shared__ u64 keptS[16];
  __shared__ int s_chg;
  const int tid = threadIdx.x;
  const int b = blockIdx.x;
  const int wv = tid >> 6, lane = tid & 63;

  float sc = (tid < KDET) ? scoreG[b * KDET + tid] : 0.0f;
  bool valid = (tid < KDET) && (sc >= SCORE_THR);

  u64 row[16];
  const u64* mrow = mat + (size_t)b * (KDET * 16) + (size_t)tid * 16;
  const int wtop = tid >> 6;
#pragma unroll
  for (int w = 0; w < 16; ++w)
    row[w] = (tid < KDET && w <= wtop) ? mrow[w] : 0ull;

  {
    u64 mb = __ballot(valid);
    if (lane == 0) keptS[wv] = mb;
  }
  __syncthreads();

  for (int it = 0; it < KDET + 1; ++it) {
    u64 sup = 0;
#pragma unroll
    for (int w = 0; w < 16; ++w) sup |= keptS[w] & row[w];
    bool nk = valid && (sup == 0ull);
    u64 nw = __ballot(nk);
    if (tid == 0) s_chg = 0;
    __syncthreads();
    if (lane == 0) {
      if (nw != keptS[wv]) s_chg = 1;
      keptS[wv] = nw;
    }
    __syncthreads();
    if (s_chg == 0) break;
  }

  if (tid < KDET) {
    bool kp = ((keptS[tid >> 6] >> (tid & 63)) & 1ull) != 0ull;
    int o1 = b * KDET + tid;
    out[o1] = kp ? sc : 0.0f;
    out[BATCH * KDET + o1] = kp ? (float)clsG[o1] : 0.0f;
    float4 bx = boxG[o1];
    float* ob = out + 2 * BATCH * KDET + (size_t)o1 * 4;
    ob[0] = kp ? bx.x : 0.0f;
    ob[1] = kp ? bx.y : 0.0f;
    ob[2] = kp ? bx.z : 0.0f;
    ob[3] = kp ? bx.w : 0.0f;
  }
}

extern "C" void kernel_launch(void* const* d_in, const int* in_sizes, int n_in,
                              void* d_out, int out_size, void* d_ws, size_t ws_size,
                              hipStream_t stream) {
  const float* cls[5]; const float* ctr[5]; const float* reg[5];
  for (int i = 0; i < 5; ++i) {
    cls[i] = (const float*)d_in[3 * i + 0];
    ctr[i] = (const float*)d_in[3 * i + 1];
    reg[i] = (const float*)d_in[3 * i + 2];
  }
  char* ws = (char*)d_ws;
  // mat region (0 .. 2,048,000) is overlaid by sb/cl8/candG, all dead before k_mat writes.
  u32* sb   = (u32*)ws;                                  // 1,092,096 B
  unsigned char* cl8 = (unsigned char*)(ws + 1092096);   //   273,024 B (dead after k_rank)
  u64* candG = (u64*)(ws + 1365120);                     //   262,144 B (dead after k_rank)
  u64* mat  = (u64*)ws;                                  // 2,048,000 B
  float*  scoreG = (float*) (ws + 2048000);              //    64,000 B
  int*    clsG   = (int*)   (ws + 2112000);              //    64,000 B
  float4* boxG   = (float4*)(ws + 2176000);              //   256,000 B
  int*    cntG   = (int*)   (ws + 2432000);              //        64 B
  u32*    maxcG  = (u32*)   (ws + 2432064);              //        64 B

  dim3 g1((NANCH / 4 + 63) / 64, BATCH);
  k_score<<<g1, dim3(64, 4), 0, stream>>>(cls[0], ctr[0], cls[1], ctr[1], cls[2], ctr[2],
                                          cls[3], ctr[3], cls[4], ctr[4], sb, (u32*)cl8);
  k_topk<<<BATCH, 1024, 0, stream>>>(sb, candG, cntG, maxcG);
  k_rank<<<dim3(8, BATCH), 256, 0, stream>>>(reg[0], reg[1], reg[2], reg[3], reg[4],
                                             cl8, candG, cntG, scoreG, clsG, boxG, maxcG);
  k_mat<<<dim3(34, BATCH), 256, 0, stream>>>(boxG, clsG, maxcG, mat);
  k_nms<<<BATCH, 1024, 0, stream>>>(mat, scoreG, clsG, boxG, (float*)d_out);
}